// Round 7
// baseline (535.434 us; speedup 1.0000x reference)
//
#include <hip/hip_runtime.h>

// x[2048,64,2] -> MLP(2->16 relu ->16) -> 8x LSTM(H=64) -> MLP(64->32 relu ->4)
// fp32 in/out. LSTM via split-bf16 MFMA (3-term, ~fp32 accuracy).
//
// Round 11: decoupled sync — late write-gate for A, early read-release for B.
//   4 dispatches, each fuses layers (2p, 2p+1). grid 256 x 512 threads, M=8.
//   Waves 0-3 (A): layer A; waves 4-7 (B): layer B. LDS counters cA, cB, cBm.
//   A@s: wait cA>=4s (intra-group) | stage x | MFMA | phase C |
//        wait cBm>=4(s-1) (B@(s-2) reads done) | h-write | bump cA.
//   B@t: wait cB>=4t, cA>=4(t+1) | preload 8x ds_read_b128 -> regs |
//        bump cBm (reads landed -> A may overwrite) | MFMA (reg operands) |
//        phase C | h-write + global | bump cB.
//   => A's MFMA overlaps B's VALU and vice versa (was: lockstep collision).
//   setprio(1) around MFMA clusters (phase diversity now exists).
//   h_A lives once in pB cols 0-63; pA is x-only. Full-wave phase C (bpermute).
//   MFMA inputs/order bit-identical to verified R9/R10 -> absmax 0.0 expected.

#define BATCH 2048
#define TT 64
#define HH 64
#define LDP 136   // pB row stride in shorts

typedef short bf16x8 __attribute__((ext_vector_type(8)));
typedef float f32x4 __attribute__((ext_vector_type(4)));

__device__ __forceinline__ float sigmoid_fast(float x) {
    return __builtin_amdgcn_rcpf(1.f + __expf(-x));
}
__device__ __forceinline__ float tanh_fast(float x) {
    float e = __expf(-2.f * x);
    e = fminf(e, 1e30f);          // keep 1+e finite so rcp>0: tanh(-big) -> -1, not NaN
    return (1.f - e) * __builtin_amdgcn_rcpf(1.f + e);
}
__device__ __forceinline__ void split2(float x, unsigned short& hi, unsigned short& lo) {
    const unsigned u = __float_as_uint(x);
    hi = (unsigned short)(u >> 16);
    const float r = x - __uint_as_float(u & 0xFFFF0000u);  // exact
    lo = (unsigned short)(__float_as_uint(r) >> 16);
}
__device__ __forceinline__ void wg_wait(int* c, int v) {
    while (__hip_atomic_load(c, __ATOMIC_ACQUIRE, __HIP_MEMORY_SCOPE_WORKGROUP) < v) {}
}
__device__ __forceinline__ void wg_bump(int* c, int lane) {
    if (lane == 0)
        __hip_atomic_fetch_add(c, 1, __ATOMIC_RELEASE, __HIP_MEMORY_SCOPE_WORKGROUP);
}

// ---------------- input MLP: 2 -> 16 relu -> 16 ----------------
__global__ __launch_bounds__(256)
void mlp_in_kernel(const float* __restrict__ x,
                   const float* __restrict__ w1, const float* __restrict__ b1,
                   const float* __restrict__ w2, const float* __restrict__ b2,
                   float* __restrict__ out) {
    const int gid = blockIdx.x * 256 + threadIdx.x;
    const float x0 = x[gid * 2 + 0];
    const float x1 = x[gid * 2 + 1];
    float hid[16];
#pragma unroll
    for (int j = 0; j < 16; ++j) {
        float v = fmaf(x1, w1[j * 2 + 1], fmaf(x0, w1[j * 2 + 0], b1[j]));
        hid[j] = fmaxf(0.f, v);
    }
    float o[16];
#pragma unroll
    for (int oo = 0; oo < 16; ++oo) {
        float acc = b2[oo];
#pragma unroll
        for (int j = 0; j < 16; ++j) acc = fmaf(hid[j], w2[oo * 16 + j], acc);
        o[oo] = acc;
    }
    float4* op = (float4*)(out + gid * 16);
#pragma unroll
    for (int q = 0; q < 4; ++q) {
        float4 v;
        v.x = o[q * 4 + 0]; v.y = o[q * 4 + 1]; v.z = o[q * 4 + 2]; v.w = o[q * 4 + 3];
        op[q] = v;
    }
}

// ---------------- fused LSTM layer pair, decoupled sync, M=8, 512 threads ----------------
// K layout (A): k in [0,IPADA) = x (pA panel); k in [IPADA,IPADA+64) = h_A (pB cols 0-63).
// K layout (B): k in [0,64) = h_A (pB cols 0-63); k in [64,128) = h_B (pB cols 64-127).
template <int IA, int IPADA>
__global__ __launch_bounds__(512, 2)
void lstm_pair(const float* __restrict__ xmlp,   // A input iff IA==16
               unsigned* __restrict__ P,          // packed h buffer (A in / B out)
               float* __restrict__ houtf,         // B out iff last
               const int last,
               const float* __restrict__ wihA, const float* __restrict__ whhA,
               const float* __restrict__ biA, const float* __restrict__ bhA,
               const float* __restrict__ wihB, const float* __restrict__ whhB,
               const float* __restrict__ biB, const float* __restrict__ bhB) {
    constexpr int KTA = (IPADA + 64) / 32;  // total k-tiles for A
    constexpr int KTX = IPADA / 32;         // k-tiles living in pA (x region)
    constexpr int LDPA = IPADA + 8;         // pA row stride (shorts); +8 keeps 16B row align
    __shared__ __align__(16) unsigned short pAh[2][16 * LDPA], pAl[2][16 * LDPA];
    __shared__ __align__(16) unsigned short pBh[2][16 * LDP], pBl[2][16 * LDP];
    __shared__ int cA, cB, cBm;

    const int tid = threadIdx.x;
    const int wv = tid >> 6, lane = tid & 63, l16 = lane & 15, quad = lane >> 4;
    const int grp = wv >> 2;   // 0 = layer A, 1 = layer B
    const int wg = wv & 3;     // j-group within layer
    const int base = blockIdx.x * 8;
    const bool lo32 = (lane < 32);
    const int bpi = (lane & 31) << 2;   // ds_bpermute byte index: partner lane-32

    if (tid == 0) { cA = 0; cB = 0; cBm = 0; }
    for (int e = tid; e < 2 * 16 * LDPA; e += 512) { (&pAh[0][0])[e] = 0; (&pAl[0][0])[e] = 0; }
    for (int e = tid; e < 2 * 16 * LDP; e += 512)  { (&pBh[0][0])[e] = 0; (&pBl[0][0])[e] = 0; }

    // per-wave layer params (wave-uniform)
    const int I    = grp ? 64 : IA;
    const int IPAD = grp ? 64 : IPADA;
    const int KT   = grp ? 4  : KTA;
    const float* wih = grp ? wihB : wihA;
    const float* whh = grp ? whhB : whhA;
    const float* bi  = grp ? biB  : biA;
    const float* bh  = grp ? bhB  : bhA;

    // --- weight B-fragments, gate-per-tile: tile gt = gate gt for j in [16wg,16wg+16) ---
    const int jg = 16 * wg + l16;
    bf16x8 bhi[4][4], blo[4][4];  // [kt][gt]
    float bsum[4];
#pragma unroll
    for (int gt = 0; gt < 4; ++gt) {
        const int n = gt * 64 + jg;
        bsum[gt] = bi[n] + bh[n];
#pragma unroll
        for (int kt = 0; kt < 4; ++kt) {
            bf16x8 vh = {0, 0, 0, 0, 0, 0, 0, 0};
            bf16x8 vl = {0, 0, 0, 0, 0, 0, 0, 0};
            if (kt < KT) {
#pragma unroll
                for (int j = 0; j < 8; ++j) {
                    const int k = kt * 32 + quad * 8 + j;
                    float w = 0.f;
                    if (k < I) w = wih[n * I + k];
                    else if (k >= IPAD) w = whh[n * 64 + (k - IPAD)];
                    unsigned short h_, l_;
                    split2(w, h_, l_);
                    vh[j] = (short)h_;
                    vl[j] = (short)l_;
                }
            }
            bhi[kt][gt] = vh;
            blo[kt][gt] = vl;
        }
    }

    // c-state: 2 cells/lane, rows row0+r, col jg
    float cs[2] = {0.f, 0.f};
    const int row0 = (quad & 1) * 4 + ((quad >> 1) << 1);

    // --- staging setup (A-group only): x(0) -> pA[0]; prefetch x(1). b32-packed. ---
    float2 xr2 = {0.f, 0.f};
    uint2 xru = {0u, 0u};
    int sr = 0, sc = 0, srd = 0;
    bool stg = false;
    if (grp == 0) {
        if (IA == 16) {
            stg = (tid < 128);
            sr = tid >> 3; sc = (tid & 7) * 2;       // sr 0..15; rows 8-15 are junk pad
            srd = base + (sr & 7);                    // clamp global read row to valid range
            if (stg) {
                xr2 = *(const float2*)&xmlp[((size_t)srd * TT + 0) * 16 + sc];
                unsigned short h0, l0, h1, l1;
                split2(xr2.x, h0, l0); split2(xr2.y, h1, l1);
                *(unsigned*)&pAh[0][sr * LDPA + sc] = ((unsigned)h1 << 16) | h0;
                *(unsigned*)&pAl[0][sr * LDPA + sc] = ((unsigned)l1 << 16) | l0;
                xr2 = *(const float2*)&xmlp[((size_t)srd * TT + 1) * 16 + sc];
            }
        } else {
            stg = true;
            sr = tid >> 5; sc = (tid & 31) * 2;
            srd = base + sr;
            xru = *(const uint2*)&P[((size_t)srd * TT + 0) * 64 + sc];
            *(unsigned*)&pAh[0][sr * LDPA + sc] = (xru.y & 0xFFFF0000u) | (xru.x >> 16);
            *(unsigned*)&pAl[0][sr * LDPA + sc] = (xru.y << 16) | (xru.x & 0xFFFFu);
            xru = *(const uint2*)&P[((size_t)srd * TT + 1) * 64 + sc];
        }
    }
    __syncthreads();   // panels + counters ready; last barrier in the kernel

    if (grp == 0) {
        // ================= group A: layer A, steps 0..63 =================
        for (int t = 0; t < TT; ++t) {
            const int pb = t & 1;
            if (t) wg_wait(&cA, 4 * t);   // intra-group only: h_A(t-1) + staging complete
            // ---- stage x(t+1) into pA[pb^1] (overwrites x(t-1), readers done by gate) ----
            if (stg) {
                if (IA == 16) {
                    unsigned short h0, l0, h1, l1;
                    split2(xr2.x, h0, l0); split2(xr2.y, h1, l1);
                    *(unsigned*)&pAh[pb ^ 1][sr * LDPA + sc] = ((unsigned)h1 << 16) | h0;
                    *(unsigned*)&pAl[pb ^ 1][sr * LDPA + sc] = ((unsigned)l1 << 16) | l0;
                    const int tp = (t + 2) & (TT - 1);
                    xr2 = *(const float2*)&xmlp[((size_t)srd * TT + tp) * 16 + sc];
                } else {
                    *(unsigned*)&pAh[pb ^ 1][sr * LDPA + sc] = (xru.y & 0xFFFF0000u) | (xru.x >> 16);
                    *(unsigned*)&pAl[pb ^ 1][sr * LDPA + sc] = (xru.y << 16) | (xru.x & 0xFFFFu);
                    const int tp = (t + 2) & (TT - 1);
                    xru = *(const uint2*)&P[((size_t)srd * TT + tp) * 64 + sc];
                }
            }
            // ---- preload A-fragments: x from pA[pb], h_A(t-1) from pB[pb^1] cols 0-63 ----
            bf16x8 ahi[4], alo[4];
#pragma unroll
            for (int kt = 0; kt < KTA; ++kt) {
                if (kt < KTX) {
                    const int aoff = l16 * LDPA + kt * 32 + quad * 8;
                    ahi[kt] = *(const bf16x8*)&pAh[pb][aoff];
                    alo[kt] = *(const bf16x8*)&pAl[pb][aoff];
                } else {
                    const int aoff = l16 * LDP + (kt - KTX) * 32 + quad * 8;
                    ahi[kt] = *(const bf16x8*)&pBh[pb ^ 1][aoff];
                    alo[kt] = *(const bf16x8*)&pBl[pb ^ 1][aoff];
                }
            }
            f32x4 a0[4], a1[4], a2[4];
#pragma unroll
            for (int gt = 0; gt < 4; ++gt) {
                a0[gt][0] = bsum[gt]; a0[gt][1] = bsum[gt];
                a0[gt][2] = bsum[gt]; a0[gt][3] = bsum[gt];
                a1[gt] = (f32x4){0.f, 0.f, 0.f, 0.f};
                a2[gt] = (f32x4){0.f, 0.f, 0.f, 0.f};
            }
            __builtin_amdgcn_s_setprio(1);
#pragma unroll
            for (int kt = 0; kt < KTA; ++kt) {
#pragma unroll
                for (int gt = 0; gt < 4; ++gt) {
                    a0[gt] = __builtin_amdgcn_mfma_f32_16x16x32_bf16(ahi[kt], bhi[kt][gt], a0[gt], 0, 0, 0);
                    a1[gt] = __builtin_amdgcn_mfma_f32_16x16x32_bf16(alo[kt], bhi[kt][gt], a1[gt], 0, 0, 0);
                    a2[gt] = __builtin_amdgcn_mfma_f32_16x16x32_bf16(ahi[kt], blo[kt][gt], a2[gt], 0, 0, 0);
                }
            }
            __builtin_amdgcn_s_setprio(0);
            // sums (exact verified order) + full-wave redistribution
            f32x4 s4[4];
#pragma unroll
            for (int gt = 0; gt < 4; ++gt) s4[gt] = (a0[gt] + a1[gt]) + a2[gt];
            float gk[4][2];
#pragma unroll
            for (int gt = 0; gt < 4; ++gt) {
#pragma unroll
                for (int r = 0; r < 2; ++r) {
                    const float up = __uint_as_float(
                        __builtin_amdgcn_ds_bpermute(bpi, __float_as_uint(s4[gt][r + 2])));
                    gk[gt][r] = lo32 ? s4[gt][r] : up;
                }
            }
            float hv[2];
#pragma unroll
            for (int r = 0; r < 2; ++r) {
                const float iv = sigmoid_fast(gk[0][r]);
                const float fv = sigmoid_fast(gk[1][r]);
                const float gv = tanh_fast(gk[2][r]);
                const float ov = sigmoid_fast(gk[3][r]);
                const float cn = fv * cs[r] + iv * gv;
                cs[r] = cn;
                hv[r] = ov * tanh_fast(cn);
            }
            // ---- late write-gate: B@(t-2) must have consumed pB[pb] cols 0-63 ----
            if (t >= 2) wg_wait(&cBm, 4 * (t - 1));
#pragma unroll
            for (int r = 0; r < 2; ++r) {
                const int R = row0 + r;
                unsigned short h_, l_;
                split2(hv[r], h_, l_);
                pBh[pb][R * LDP + jg] = h_;   // h_A(t): B's x-region AND A's own recurrence
                pBl[pb][R * LDP + jg] = l_;
            }
            wg_bump(&cA, lane);
        }
    } else {
        // ================= group B: layer B, steps 0..63 =================
        for (int t = 0; t < TT; ++t) {
            const int pb = t & 1;
            if (t) wg_wait(&cB, 4 * t);
            wg_wait(&cA, 4 * (t + 1));   // h_A(t) complete
            // ---- preload all A-fragments to regs, then RELEASE the panel early ----
            bf16x8 ahi[4], alo[4];
#pragma unroll
            for (int kt = 0; kt < 4; ++kt) {
                const int aoff = l16 * LDP + kt * 32 + quad * 8;
                ahi[kt] = *(const bf16x8*)&pBh[pb][aoff];
                alo[kt] = *(const bf16x8*)&pBl[pb][aoff];
            }
            wg_bump(&cBm, lane);   // release: A may overwrite pB[pb] cols 0-63
            f32x4 a0[4], a1[4], a2[4];
#pragma unroll
            for (int gt = 0; gt < 4; ++gt) {
                a0[gt][0] = bsum[gt]; a0[gt][1] = bsum[gt];
                a0[gt][2] = bsum[gt]; a0[gt][3] = bsum[gt];
                a1[gt] = (f32x4){0.f, 0.f, 0.f, 0.f};
                a2[gt] = (f32x4){0.f, 0.f, 0.f, 0.f};
            }
            __builtin_amdgcn_s_setprio(1);
#pragma unroll
            for (int kt = 0; kt < 4; ++kt) {
#pragma unroll
                for (int gt = 0; gt < 4; ++gt) {
                    a0[gt] = __builtin_amdgcn_mfma_f32_16x16x32_bf16(ahi[kt], bhi[kt][gt], a0[gt], 0, 0, 0);
                    a1[gt] = __builtin_amdgcn_mfma_f32_16x16x32_bf16(alo[kt], bhi[kt][gt], a1[gt], 0, 0, 0);
                    a2[gt] = __builtin_amdgcn_mfma_f32_16x16x32_bf16(ahi[kt], blo[kt][gt], a2[gt], 0, 0, 0);
                }
            }
            __builtin_amdgcn_s_setprio(0);
            f32x4 s4[4];
#pragma unroll
            for (int gt = 0; gt < 4; ++gt) s4[gt] = (a0[gt] + a1[gt]) + a2[gt];
            float gk[4][2];
#pragma unroll
            for (int gt = 0; gt < 4; ++gt) {
#pragma unroll
                for (int r = 0; r < 2; ++r) {
                    const float up = __uint_as_float(
                        __builtin_amdgcn_ds_bpermute(bpi, __float_as_uint(s4[gt][r + 2])));
                    gk[gt][r] = lo32 ? s4[gt][r] : up;
                }
            }
#pragma unroll
            for (int r = 0; r < 2; ++r) {
                const float iv = sigmoid_fast(gk[0][r]);
                const float fv = sigmoid_fast(gk[1][r]);
                const float gv = tanh_fast(gk[2][r]);
                const float ov = sigmoid_fast(gk[3][r]);
                const float cn = fv * cs[r] + iv * gv;
                cs[r] = cn;
                const float h = ov * tanh_fast(cn);
                const int R = row0 + r;
                unsigned short h_, l_;
                split2(h, h_, l_);
                pBh[pb ^ 1][R * LDP + 64 + jg] = h_;   // h_B recurrence (cols 64-127)
                pBl[pb ^ 1][R * LDP + 64 + jg] = l_;
                if (!last) {
                    P[((size_t)(base + R) * TT + t) * 64 + jg] =
                        ((unsigned)h_ << 16) | (unsigned)l_;
                } else {
                    houtf[((size_t)(base + R) * TT + t) * HH + jg] = h;
                }
            }
            wg_bump(&cB, lane);
        }
    }
}

// ---------------- output MLP: 64 -> 32 relu -> 4 ----------------
__global__ __launch_bounds__(256)
void mlp_out_kernel(const float* __restrict__ hin,
                    const float* __restrict__ wo1, const float* __restrict__ bo1,
                    const float* __restrict__ wo2, const float* __restrict__ bo2,
                    float* __restrict__ out) {
    __shared__ __align__(16) float wo1_s[32 * 64];
    __shared__ float bo1_s[32];
    __shared__ float wo2_s[4 * 32];
    __shared__ float bo2_s[4];
    const int tid = threadIdx.x;
    for (int e = tid; e < 32 * 64; e += 256) wo1_s[e] = wo1[e];
    if (tid < 32) bo1_s[tid] = bo1[tid];
    if (tid < 128) wo2_s[tid] = wo2[tid];
    if (tid < 4) bo2_s[tid] = bo2[tid];
    __syncthreads();

    const int gid = blockIdx.x * 256 + tid;
    const float4* hv = (const float4*)(hin + gid * 64);
    float4 h[16];
#pragma unroll
    for (int q = 0; q < 16; ++q) h[q] = hv[q];

    float m1[32];
#pragma unroll
    for (int o = 0; o < 32; ++o) {
        float acc = bo1_s[o];
        const float4* wrow = (const float4*)(wo1_s + o * 64);
#pragma unroll
        for (int q = 0; q < 16; ++q) {
            const float4 w = wrow[q];
            acc = fmaf(h[q].x, w.x, acc);
            acc = fmaf(h[q].y, w.y, acc);
            acc = fmaf(h[q].z, w.z, acc);
            acc = fmaf(h[q].w, w.w, acc);
        }
        m1[o] = fmaxf(0.f, acc);
    }
    float r[4];
#pragma unroll
    for (int q = 0; q < 4; ++q) {
        float acc = bo2_s[q];
#pragma unroll
        for (int o = 0; o < 32; ++o) acc = fmaf(m1[o], wo2_s[q * 32 + o], acc);
        r[q] = acc;
    }
    float4 res;
    res.x = r[0]; res.y = r[1]; res.z = r[2]; res.w = r[3];
    ((float4*)out)[gid] = res;
}

extern "C" void kernel_launch(void* const* d_in, const int* in_sizes, int n_in,
                              void* d_out, int out_size, void* d_ws, size_t ws_size,
                              hipStream_t stream) {
    const float* x     = (const float*)d_in[0];
    const float* w1    = (const float*)d_in[1];
    const float* b1    = (const float*)d_in[2];
    const float* w2    = (const float*)d_in[3];
    const float* b2    = (const float*)d_in[4];
    const float* w_ih0 = (const float*)d_in[5];
    const float* w_hh0 = (const float*)d_in[6];
    const float* b_ih0 = (const float*)d_in[7];
    const float* b_hh0 = (const float*)d_in[8];
    const float* w_ih  = (const float*)d_in[9];
    const float* w_hh  = (const float*)d_in[10];
    const float* b_ih  = (const float*)d_in[11];
    const float* b_hh  = (const float*)d_in[12];
    const float* wo1   = (const float*)d_in[13];
    const float* bo1   = (const float*)d_in[14];
    const float* wo2   = (const float*)d_in[15];
    const float* bo2   = (const float*)d_in[16];

    // workspace: buf_mlp B*T*16 f32 (8 MB) | P B*T*64 u32 packed (32 MB) | bufH B*T*64 f32 (32 MB)
    float* buf_mlp = (float*)d_ws;
    unsigned* P = (unsigned*)(buf_mlp + (size_t)BATCH * TT * 16);
    float* bufH = (float*)(P + (size_t)BATCH * TT * 64);

    const int nbt_blocks = (BATCH * TT) / 256;  // 512

    mlp_in_kernel<<<nbt_blocks, 256, 0, stream>>>(x, w1, b1, w2, b2, buf_mlp);

    // pair 0: layers 0,1
    lstm_pair<16, 32><<<BATCH / 8, 512, 0, stream>>>(
        buf_mlp, P, bufH, 0,
        w_ih0, w_hh0, b_ih0, b_hh0,
        w_ih + (size_t)0 * 256 * 64, w_hh + (size_t)0 * 256 * 64, b_ih + 0 * 256, b_hh + 0 * 256);

    // pairs 1..3: layers (2,3), (4,5), (6,7) -> w_ih/w_hh indices (1,2), (3,4), (5,6)
    for (int p = 1; p < 4; ++p) {
        const int la = 2 * p - 1, lb = 2 * p;  // indices into w_ih/w_hh arrays (layer l -> idx l-1)
        lstm_pair<64, 64><<<BATCH / 8, 512, 0, stream>>>(
            buf_mlp, P, bufH, (p == 3) ? 1 : 0,
            w_ih + (size_t)la * 256 * 64, w_hh + (size_t)la * 256 * 64,
            b_ih + la * 256, b_hh + la * 256,
            w_ih + (size_t)lb * 256 * 64, w_hh + (size_t)lb * 256 * 64,
            b_ih + lb * 256, b_hh + lb * 256);
    }

    mlp_out_kernel<<<nbt_blocks, 256, 0, stream>>>(bufH, wo1, bo1, wo2, bo2, (float*)d_out);
}

// Round 8
// 509.160 us; speedup vs baseline: 1.0516x; 1.0516x over previous
//
#include <hip/hip_runtime.h>

// x[2048,64,2] -> MLP(2->16 relu ->16) -> 8x LSTM(H=64) -> MLP(64->32 relu ->4)
// fp32 in/out. LSTM via split-bf16 MFMA (3-term, ~fp32 accuracy).
//
// Round 12: elastic A->B handoff via 4-deep h_A ring (3-step slack).
//   4 dispatches, each fuses layers (2p, 2p+1). grid 256 x 512 threads, M=8.
//   Waves 0-3 (A): layer A; waves 4-7 (B): layer B, lagging 1-3 steps (elastic).
//   LDS: pA (x panel, 2-deep parity) | pHA ring (4 slots, h_A) | pHB (2-deep, h_B).
//   A@t: wait cA>=4t | stage x(t+1) | preload x(pA[pb]) + h_A(t-1)(ring (t-1)&3) |
//        MFMA | phase C | gate cBm>=4(t-3) | h_A(t) -> ring t&3 | bump cA.
//   B@t: wait cB>=4t, cA>=4(t+1) | preload h_A(t)(ring t&3) + h_B(t-1)(pHB) |
//        bump cBm | MFMA | phase C | h_B -> pHB + global | bump cB.
//   With B lagging, BOTH cross-group waits are pre-satisfied in steady state ->
//   no wake-up latency on the recurrence chain (R11's regression cause), and
//   A/B phases drift -> MFMA/VALU pipes of the two waves/SIMD interleave.
//   setprio(1) around MFMA clusters. Full-wave phase C (bpermute).
//   MFMA inputs/order bit-identical to verified R9/R10/R11 -> absmax 0.0.

#define BATCH 2048
#define TT 64
#define HH 64
#define RS 72     // h-panel row stride in shorts (64 cols + 8 pad)

typedef short bf16x8 __attribute__((ext_vector_type(8)));
typedef float f32x4 __attribute__((ext_vector_type(4)));

__device__ __forceinline__ float sigmoid_fast(float x) {
    return __builtin_amdgcn_rcpf(1.f + __expf(-x));
}
__device__ __forceinline__ float tanh_fast(float x) {
    float e = __expf(-2.f * x);
    e = fminf(e, 1e30f);          // keep 1+e finite so rcp>0: tanh(-big) -> -1, not NaN
    return (1.f - e) * __builtin_amdgcn_rcpf(1.f + e);
}
__device__ __forceinline__ void split2(float x, unsigned short& hi, unsigned short& lo) {
    const unsigned u = __float_as_uint(x);
    hi = (unsigned short)(u >> 16);
    const float r = x - __uint_as_float(u & 0xFFFF0000u);  // exact
    lo = (unsigned short)(__float_as_uint(r) >> 16);
}
__device__ __forceinline__ void wg_wait(int* c, int v) {
    while (__hip_atomic_load(c, __ATOMIC_ACQUIRE, __HIP_MEMORY_SCOPE_WORKGROUP) < v) {}
}
__device__ __forceinline__ void wg_bump(int* c, int lane) {
    if (lane == 0)
        __hip_atomic_fetch_add(c, 1, __ATOMIC_RELEASE, __HIP_MEMORY_SCOPE_WORKGROUP);
}

// ---------------- input MLP: 2 -> 16 relu -> 16 ----------------
__global__ __launch_bounds__(256)
void mlp_in_kernel(const float* __restrict__ x,
                   const float* __restrict__ w1, const float* __restrict__ b1,
                   const float* __restrict__ w2, const float* __restrict__ b2,
                   float* __restrict__ out) {
    const int gid = blockIdx.x * 256 + threadIdx.x;
    const float x0 = x[gid * 2 + 0];
    const float x1 = x[gid * 2 + 1];
    float hid[16];
#pragma unroll
    for (int j = 0; j < 16; ++j) {
        float v = fmaf(x1, w1[j * 2 + 1], fmaf(x0, w1[j * 2 + 0], b1[j]));
        hid[j] = fmaxf(0.f, v);
    }
    float o[16];
#pragma unroll
    for (int oo = 0; oo < 16; ++oo) {
        float acc = b2[oo];
#pragma unroll
        for (int j = 0; j < 16; ++j) acc = fmaf(hid[j], w2[oo * 16 + j], acc);
        o[oo] = acc;
    }
    float4* op = (float4*)(out + gid * 16);
#pragma unroll
    for (int q = 0; q < 4; ++q) {
        float4 v;
        v.x = o[q * 4 + 0]; v.y = o[q * 4 + 1]; v.z = o[q * 4 + 2]; v.w = o[q * 4 + 3];
        op[q] = v;
    }
}

// ---------------- fused LSTM layer pair, ring handoff, M=8, 512 threads ----------------
// K layout (A): k in [0,IPADA) = x (pA); k in [IPADA,IPADA+64) = h_A (ring slot t-1).
// K layout (B): k in [0,64) = h_A (ring slot t); k in [64,128) = h_B (pHB).
template <int IA, int IPADA>
__global__ __launch_bounds__(512, 2)
void lstm_pair(const float* __restrict__ xmlp,   // A input iff IA==16
               unsigned* __restrict__ P,          // packed h buffer (A in / B out)
               float* __restrict__ houtf,         // B out iff last
               const int last,
               const float* __restrict__ wihA, const float* __restrict__ whhA,
               const float* __restrict__ biA, const float* __restrict__ bhA,
               const float* __restrict__ wihB, const float* __restrict__ whhB,
               const float* __restrict__ biB, const float* __restrict__ bhB) {
    constexpr int KTA = (IPADA + 64) / 32;  // total k-tiles for A
    constexpr int KTX = IPADA / 32;         // k-tiles living in pA (x region)
    constexpr int LDPA = IPADA + 8;         // pA row stride (shorts); keeps 16B row align
    __shared__ __align__(16) unsigned short pAh[2][16 * LDPA], pAl[2][16 * LDPA];
    __shared__ __align__(16) unsigned short rHh[4][16 * RS], rHl[4][16 * RS];  // h_A ring
    __shared__ __align__(16) unsigned short pHh[2][16 * RS], pHl[2][16 * RS];  // h_B parity
    __shared__ int cA, cB, cBm;

    const int tid = threadIdx.x;
    const int wv = tid >> 6, lane = tid & 63, l16 = lane & 15, quad = lane >> 4;
    const int grp = wv >> 2;   // 0 = layer A, 1 = layer B
    const int wg = wv & 3;     // j-group within layer
    const int base = blockIdx.x * 8;
    const bool lo32 = (lane < 32);
    const int bpi = (lane & 31) << 2;   // ds_bpermute byte index: partner lane-32

    if (tid == 0) { cA = 0; cB = 0; cBm = 0; }
    for (int e = tid; e < 2 * 16 * LDPA; e += 512) { (&pAh[0][0])[e] = 0; (&pAl[0][0])[e] = 0; }
    for (int e = tid; e < 4 * 16 * RS; e += 512)   { (&rHh[0][0])[e] = 0; (&rHl[0][0])[e] = 0; }
    for (int e = tid; e < 2 * 16 * RS; e += 512)   { (&pHh[0][0])[e] = 0; (&pHl[0][0])[e] = 0; }

    // per-wave layer params (wave-uniform)
    const int I    = grp ? 64 : IA;
    const int IPAD = grp ? 64 : IPADA;
    const int KT   = grp ? 4  : KTA;
    const float* wih = grp ? wihB : wihA;
    const float* whh = grp ? whhB : whhA;
    const float* bi  = grp ? biB  : biA;
    const float* bh  = grp ? bhB  : bhA;

    // --- weight B-fragments, gate-per-tile: tile gt = gate gt for j in [16wg,16wg+16) ---
    const int jg = 16 * wg + l16;
    bf16x8 bhi[4][4], blo[4][4];  // [kt][gt]
    float bsum[4];
#pragma unroll
    for (int gt = 0; gt < 4; ++gt) {
        const int n = gt * 64 + jg;
        bsum[gt] = bi[n] + bh[n];
#pragma unroll
        for (int kt = 0; kt < 4; ++kt) {
            bf16x8 vh = {0, 0, 0, 0, 0, 0, 0, 0};
            bf16x8 vl = {0, 0, 0, 0, 0, 0, 0, 0};
            if (kt < KT) {
#pragma unroll
                for (int j = 0; j < 8; ++j) {
                    const int k = kt * 32 + quad * 8 + j;
                    float w = 0.f;
                    if (k < I) w = wih[n * I + k];
                    else if (k >= IPAD) w = whh[n * 64 + (k - IPAD)];
                    unsigned short h_, l_;
                    split2(w, h_, l_);
                    vh[j] = (short)h_;
                    vl[j] = (short)l_;
                }
            }
            bhi[kt][gt] = vh;
            blo[kt][gt] = vl;
        }
    }

    // c-state: 2 cells/lane, rows row0+r, col jg
    float cs[2] = {0.f, 0.f};
    const int row0 = (quad & 1) * 4 + ((quad >> 1) << 1);

    // --- staging setup (A-group only): x(0) -> pA[0]; prefetch x(1). b32-packed. ---
    float2 xr2 = {0.f, 0.f};
    uint2 xru = {0u, 0u};
    int sr = 0, sc = 0, srd = 0;
    bool stg = false;
    if (grp == 0) {
        if (IA == 16) {
            stg = (tid < 128);
            sr = tid >> 3; sc = (tid & 7) * 2;       // sr 0..15; rows 8-15 are junk pad
            srd = base + (sr & 7);                    // clamp global read row to valid range
            if (stg) {
                xr2 = *(const float2*)&xmlp[((size_t)srd * TT + 0) * 16 + sc];
                unsigned short h0, l0, h1, l1;
                split2(xr2.x, h0, l0); split2(xr2.y, h1, l1);
                *(unsigned*)&pAh[0][sr * LDPA + sc] = ((unsigned)h1 << 16) | h0;
                *(unsigned*)&pAl[0][sr * LDPA + sc] = ((unsigned)l1 << 16) | l0;
                xr2 = *(const float2*)&xmlp[((size_t)srd * TT + 1) * 16 + sc];
            }
        } else {
            stg = true;
            sr = tid >> 5; sc = (tid & 31) * 2;
            srd = base + sr;
            xru = *(const uint2*)&P[((size_t)srd * TT + 0) * 64 + sc];
            *(unsigned*)&pAh[0][sr * LDPA + sc] = (xru.y & 0xFFFF0000u) | (xru.x >> 16);
            *(unsigned*)&pAl[0][sr * LDPA + sc] = (xru.y << 16) | (xru.x & 0xFFFFu);
            xru = *(const uint2*)&P[((size_t)srd * TT + 1) * 64 + sc];
        }
    }
    __syncthreads();   // panels + counters ready; last barrier in the kernel

    if (grp == 0) {
        // ================= group A: layer A, steps 0..63 =================
        for (int t = 0; t < TT; ++t) {
            const int pb = t & 1;
            const int rsl = t & 3;          // ring slot to write (h_A(t))
            const int rpr = (t + 3) & 3;    // ring slot to read (h_A(t-1))
            if (t) wg_wait(&cA, 4 * t);     // own group: h_A(t-1) + staging complete
            // ---- stage x(t+1) into pA[pb^1] (readers done: own group gate) ----
            if (stg) {
                if (IA == 16) {
                    unsigned short h0, l0, h1, l1;
                    split2(xr2.x, h0, l0); split2(xr2.y, h1, l1);
                    *(unsigned*)&pAh[pb ^ 1][sr * LDPA + sc] = ((unsigned)h1 << 16) | h0;
                    *(unsigned*)&pAl[pb ^ 1][sr * LDPA + sc] = ((unsigned)l1 << 16) | l0;
                    const int tp = (t + 2) & (TT - 1);
                    xr2 = *(const float2*)&xmlp[((size_t)srd * TT + tp) * 16 + sc];
                } else {
                    *(unsigned*)&pAh[pb ^ 1][sr * LDPA + sc] = (xru.y & 0xFFFF0000u) | (xru.x >> 16);
                    *(unsigned*)&pAl[pb ^ 1][sr * LDPA + sc] = (xru.y << 16) | (xru.x & 0xFFFFu);
                    const int tp = (t + 2) & (TT - 1);
                    xru = *(const uint2*)&P[((size_t)srd * TT + tp) * 64 + sc];
                }
            }
            // ---- preload A-fragments: x from pA[pb], h_A(t-1) from ring slot rpr ----
            bf16x8 ahi[4], alo[4];
#pragma unroll
            for (int kt = 0; kt < KTA; ++kt) {
                if (kt < KTX) {
                    const int aoff = l16 * LDPA + kt * 32 + quad * 8;
                    ahi[kt] = *(const bf16x8*)&pAh[pb][aoff];
                    alo[kt] = *(const bf16x8*)&pAl[pb][aoff];
                } else {
                    const int aoff = l16 * RS + (kt - KTX) * 32 + quad * 8;
                    ahi[kt] = *(const bf16x8*)&rHh[rpr][aoff];
                    alo[kt] = *(const bf16x8*)&rHl[rpr][aoff];
                }
            }
            f32x4 a0[4], a1[4], a2[4];
#pragma unroll
            for (int gt = 0; gt < 4; ++gt) {
                a0[gt][0] = bsum[gt]; a0[gt][1] = bsum[gt];
                a0[gt][2] = bsum[gt]; a0[gt][3] = bsum[gt];
                a1[gt] = (f32x4){0.f, 0.f, 0.f, 0.f};
                a2[gt] = (f32x4){0.f, 0.f, 0.f, 0.f};
            }
            __builtin_amdgcn_s_setprio(1);
#pragma unroll
            for (int kt = 0; kt < KTA; ++kt) {
#pragma unroll
                for (int gt = 0; gt < 4; ++gt) {
                    a0[gt] = __builtin_amdgcn_mfma_f32_16x16x32_bf16(ahi[kt], bhi[kt][gt], a0[gt], 0, 0, 0);
                    a1[gt] = __builtin_amdgcn_mfma_f32_16x16x32_bf16(alo[kt], bhi[kt][gt], a1[gt], 0, 0, 0);
                    a2[gt] = __builtin_amdgcn_mfma_f32_16x16x32_bf16(ahi[kt], blo[kt][gt], a2[gt], 0, 0, 0);
                }
            }
            __builtin_amdgcn_s_setprio(0);
            // sums (exact verified order) + full-wave redistribution
            f32x4 s4[4];
#pragma unroll
            for (int gt = 0; gt < 4; ++gt) s4[gt] = (a0[gt] + a1[gt]) + a2[gt];
            float gk[4][2];
#pragma unroll
            for (int gt = 0; gt < 4; ++gt) {
#pragma unroll
                for (int r = 0; r < 2; ++r) {
                    const float up = __uint_as_float(
                        __builtin_amdgcn_ds_bpermute(bpi, __float_as_uint(s4[gt][r + 2])));
                    gk[gt][r] = lo32 ? s4[gt][r] : up;
                }
            }
            float hv[2];
#pragma unroll
            for (int r = 0; r < 2; ++r) {
                const float iv = sigmoid_fast(gk[0][r]);
                const float fv = sigmoid_fast(gk[1][r]);
                const float gv = tanh_fast(gk[2][r]);
                const float ov = sigmoid_fast(gk[3][r]);
                const float cn = fv * cs[r] + iv * gv;
                cs[r] = cn;
                hv[r] = ov * tanh_fast(cn);
            }
            // ---- overwrite gate: B@(t-4) must have preloaded ring slot rsl ----
            if (t >= 4) wg_wait(&cBm, 4 * (t - 3));
#pragma unroll
            for (int r = 0; r < 2; ++r) {
                const int R = row0 + r;
                unsigned short h_, l_;
                split2(hv[r], h_, l_);
                rHh[rsl][R * RS + jg] = h_;   // h_A(t) -> ring slot t&3
                rHl[rsl][R * RS + jg] = l_;
            }
            wg_bump(&cA, lane);
        }
    } else {
        // ================= group B: layer B, steps 0..63 =================
        for (int t = 0; t < TT; ++t) {
            const int pb = t & 1;
            const int rsl = t & 3;          // ring slot holding h_A(t)
            if (t) wg_wait(&cB, 4 * t);
            wg_wait(&cA, 4 * (t + 1));      // h_A(t) complete (pre-satisfied when lagging)
            // ---- preload: h_A(t) from ring, h_B(t-1) from pHB[(t-1)&1] ----
            bf16x8 ahi[4], alo[4];
#pragma unroll
            for (int kt = 0; kt < 2; ++kt) {
                const int aoff = l16 * RS + kt * 32 + quad * 8;
                ahi[kt] = *(const bf16x8*)&rHh[rsl][aoff];
                alo[kt] = *(const bf16x8*)&rHl[rsl][aoff];
            }
#pragma unroll
            for (int kt = 2; kt < 4; ++kt) {
                const int aoff = l16 * RS + (kt - 2) * 32 + quad * 8;
                ahi[kt] = *(const bf16x8*)&pHh[pb ^ 1][aoff];
                alo[kt] = *(const bf16x8*)&pHl[pb ^ 1][aoff];
            }
            wg_bump(&cBm, lane);   // release: A may overwrite ring slot rsl (at t+4)
            f32x4 a0[4], a1[4], a2[4];
#pragma unroll
            for (int gt = 0; gt < 4; ++gt) {
                a0[gt][0] = bsum[gt]; a0[gt][1] = bsum[gt];
                a0[gt][2] = bsum[gt]; a0[gt][3] = bsum[gt];
                a1[gt] = (f32x4){0.f, 0.f, 0.f, 0.f};
                a2[gt] = (f32x4){0.f, 0.f, 0.f, 0.f};
            }
            __builtin_amdgcn_s_setprio(1);
#pragma unroll
            for (int kt = 0; kt < 4; ++kt) {
#pragma unroll
                for (int gt = 0; gt < 4; ++gt) {
                    a0[gt] = __builtin_amdgcn_mfma_f32_16x16x32_bf16(ahi[kt], bhi[kt][gt], a0[gt], 0, 0, 0);
                    a1[gt] = __builtin_amdgcn_mfma_f32_16x16x32_bf16(alo[kt], bhi[kt][gt], a1[gt], 0, 0, 0);
                    a2[gt] = __builtin_amdgcn_mfma_f32_16x16x32_bf16(ahi[kt], blo[kt][gt], a2[gt], 0, 0, 0);
                }
            }
            __builtin_amdgcn_s_setprio(0);
            f32x4 s4[4];
#pragma unroll
            for (int gt = 0; gt < 4; ++gt) s4[gt] = (a0[gt] + a1[gt]) + a2[gt];
            float gk[4][2];
#pragma unroll
            for (int gt = 0; gt < 4; ++gt) {
#pragma unroll
                for (int r = 0; r < 2; ++r) {
                    const float up = __uint_as_float(
                        __builtin_amdgcn_ds_bpermute(bpi, __float_as_uint(s4[gt][r + 2])));
                    gk[gt][r] = lo32 ? s4[gt][r] : up;
                }
            }
#pragma unroll
            for (int r = 0; r < 2; ++r) {
                const float iv = sigmoid_fast(gk[0][r]);
                const float fv = sigmoid_fast(gk[1][r]);
                const float gv = tanh_fast(gk[2][r]);
                const float ov = sigmoid_fast(gk[3][r]);
                const float cn = fv * cs[r] + iv * gv;
                cs[r] = cn;
                const float h = ov * tanh_fast(cn);
                const int R = row0 + r;
                unsigned short h_, l_;
                split2(h, h_, l_);
                pHh[pb][R * RS + jg] = h_;   // h_B(t) recurrence
                pHl[pb][R * RS + jg] = l_;
                if (!last) {
                    P[((size_t)(base + R) * TT + t) * 64 + jg] =
                        ((unsigned)h_ << 16) | (unsigned)l_;
                } else {
                    houtf[((size_t)(base + R) * TT + t) * HH + jg] = h;
                }
            }
            wg_bump(&cB, lane);
        }
    }
}

// ---------------- output MLP: 64 -> 32 relu -> 4 ----------------
__global__ __launch_bounds__(256)
void mlp_out_kernel(const float* __restrict__ hin,
                    const float* __restrict__ wo1, const float* __restrict__ bo1,
                    const float* __restrict__ wo2, const float* __restrict__ bo2,
                    float* __restrict__ out) {
    __shared__ __align__(16) float wo1_s[32 * 64];
    __shared__ float bo1_s[32];
    __shared__ float wo2_s[4 * 32];
    __shared__ float bo2_s[4];
    const int tid = threadIdx.x;
    for (int e = tid; e < 32 * 64; e += 256) wo1_s[e] = wo1[e];
    if (tid < 32) bo1_s[tid] = bo1[tid];
    if (tid < 128) wo2_s[tid] = wo2[tid];
    if (tid < 4) bo2_s[tid] = bo2[tid];
    __syncthreads();

    const int gid = blockIdx.x * 256 + tid;
    const float4* hv = (const float4*)(hin + gid * 64);
    float4 h[16];
#pragma unroll
    for (int q = 0; q < 16; ++q) h[q] = hv[q];

    float m1[32];
#pragma unroll
    for (int o = 0; o < 32; ++o) {
        float acc = bo1_s[o];
        const float4* wrow = (const float4*)(wo1_s + o * 64);
#pragma unroll
        for (int q = 0; q < 16; ++q) {
            const float4 w = wrow[q];
            acc = fmaf(h[q].x, w.x, acc);
            acc = fmaf(h[q].y, w.y, acc);
            acc = fmaf(h[q].z, w.z, acc);
            acc = fmaf(h[q].w, w.w, acc);
        }
        m1[o] = fmaxf(0.f, acc);
    }
    float r[4];
#pragma unroll
    for (int q = 0; q < 4; ++q) {
        float acc = bo2_s[q];
#pragma unroll
        for (int o = 0; o < 32; ++o) acc = fmaf(m1[o], wo2_s[q * 32 + o], acc);
        r[q] = acc;
    }
    float4 res;
    res.x = r[0]; res.y = r[1]; res.z = r[2]; res.w = r[3];
    ((float4*)out)[gid] = res;
}

extern "C" void kernel_launch(void* const* d_in, const int* in_sizes, int n_in,
                              void* d_out, int out_size, void* d_ws, size_t ws_size,
                              hipStream_t stream) {
    const float* x     = (const float*)d_in[0];
    const float* w1    = (const float*)d_in[1];
    const float* b1    = (const float*)d_in[2];
    const float* w2    = (const float*)d_in[3];
    const float* b2    = (const float*)d_in[4];
    const float* w_ih0 = (const float*)d_in[5];
    const float* w_hh0 = (const float*)d_in[6];
    const float* b_ih0 = (const float*)d_in[7];
    const float* b_hh0 = (const float*)d_in[8];
    const float* w_ih  = (const float*)d_in[9];
    const float* w_hh  = (const float*)d_in[10];
    const float* b_ih  = (const float*)d_in[11];
    const float* b_hh  = (const float*)d_in[12];
    const float* wo1   = (const float*)d_in[13];
    const float* bo1   = (const float*)d_in[14];
    const float* wo2   = (const float*)d_in[15];
    const float* bo2   = (const float*)d_in[16];

    // workspace: buf_mlp B*T*16 f32 (8 MB) | P B*T*64 u32 packed (32 MB) | bufH B*T*64 f32 (32 MB)
    float* buf_mlp = (float*)d_ws;
    unsigned* P = (unsigned*)(buf_mlp + (size_t)BATCH * TT * 16);
    float* bufH = (float*)(P + (size_t)BATCH * TT * 64);

    const int nbt_blocks = (BATCH * TT) / 256;  // 512

    mlp_in_kernel<<<nbt_blocks, 256, 0, stream>>>(x, w1, b1, w2, b2, buf_mlp);

    // pair 0: layers 0,1
    lstm_pair<16, 32><<<BATCH / 8, 512, 0, stream>>>(
        buf_mlp, P, bufH, 0,
        w_ih0, w_hh0, b_ih0, b_hh0,
        w_ih + (size_t)0 * 256 * 64, w_hh + (size_t)0 * 256 * 64, b_ih + 0 * 256, b_hh + 0 * 256);

    // pairs 1..3: layers (2,3), (4,5), (6,7) -> w_ih/w_hh indices (1,2), (3,4), (5,6)
    for (int p = 1; p < 4; ++p) {
        const int la = 2 * p - 1, lb = 2 * p;  // indices into w_ih/w_hh arrays (layer l -> idx l-1)
        lstm_pair<64, 64><<<BATCH / 8, 512, 0, stream>>>(
            buf_mlp, P, bufH, (p == 3) ? 1 : 0,
            w_ih + (size_t)la * 256 * 64, w_hh + (size_t)la * 256 * 64,
            b_ih + la * 256, b_hh + la * 256,
            w_ih + (size_t)lb * 256 * 64, w_hh + (size_t)lb * 256 * 64,
            b_ih + lb * 256, b_hh + lb * 256);
    }

    mlp_out_kernel<<<nbt_blocks, 256, 0, stream>>>(bufH, wo1, bo1, wo2, bo2, (float*)d_out);
}